// Round 3
// baseline (2997.692 us; speedup 1.0000x reference)
//
#include <hip/hip_runtime.h>
#include <hip/hip_bf16.h>
#include <math.h>

#define T_SEQ 4096
#define EMB   1024
#define NH    8
#define HD    128
#define HALF  64

typedef __hip_bfloat16 bf16;

static __device__ __forceinline__ float b2f(bf16 v) { return __bfloat162float(v); }
static __device__ __forceinline__ bf16  f2b(float v) { return __float2bfloat16(v); }

// ---------------------------------------------------------------------------
// QKV projection: C[4096,1024] = x[4096,1024] @ W[1024,1024], z selects q/k/v
// fp32 inputs, 64x64 tile, BK=16, 256 threads, 4x4/thread, fp32 acc, bf16 out
// ---------------------------------------------------------------------------
__global__ __launch_bounds__(256) void qkv_gemm(
    const float* __restrict__ x,
    const float* __restrict__ wq, const float* __restrict__ wk, const float* __restrict__ wv,
    bf16* __restrict__ qb, bf16* __restrict__ kb, bf16* __restrict__ vb)
{
    const float* B = (blockIdx.z == 0) ? wq : (blockIdx.z == 1) ? wk : wv;
    bf16*        C = (blockIdx.z == 0) ? qb : (blockIdx.z == 1) ? kb : vb;
    const int m0 = blockIdx.y * 64;
    const int n0 = blockIdx.x * 64;
    __shared__ float As[16][65];   // [k][m], +1 pad
    __shared__ float Bs[16][65];   // [k][n]
    const int tid = threadIdx.x;
    const int tx = tid & 15, ty = tid >> 4;
    float acc[4][4] = {};
    for (int k0 = 0; k0 < EMB; k0 += 16) {
        {   // A tile: 64 rows(m) x 16 cols(k); 4 consecutive k per thread (float4)
            int e = tid * 4;
            int m = e >> 4, kk = e & 15;
            const float4 f = *(const float4*)(x + (size_t)(m0 + m) * EMB + k0 + kk);
            As[kk+0][m] = f.x; As[kk+1][m] = f.y; As[kk+2][m] = f.z; As[kk+3][m] = f.w;
        }
        {   // B tile: 16 rows(k) x 64 cols(n); 4 consecutive n per thread (float4)
            int e = tid * 4;
            int kk = e >> 6, n = e & 63;
            const float4 f = *(const float4*)(B + (size_t)(k0 + kk) * EMB + n0 + n);
            Bs[kk][n+0] = f.x; Bs[kk][n+1] = f.y; Bs[kk][n+2] = f.z; Bs[kk][n+3] = f.w;
        }
        __syncthreads();
        #pragma unroll
        for (int kk = 0; kk < 16; ++kk) {
            float a[4], b[4];
            #pragma unroll
            for (int i = 0; i < 4; ++i) a[i] = As[kk][ty*4+i];
            #pragma unroll
            for (int j = 0; j < 4; ++j) b[j] = Bs[kk][tx*4+j];
            #pragma unroll
            for (int i = 0; i < 4; ++i)
                #pragma unroll
                for (int j = 0; j < 4; ++j)
                    acc[i][j] += a[i] * b[j];
        }
        __syncthreads();
    }
    #pragma unroll
    for (int i = 0; i < 4; ++i)
        #pragma unroll
        for (int j = 0; j < 4; ++j)
            C[(size_t)(m0 + ty*4+i) * EMB + n0 + tx*4+j] = f2b(acc[i][j]);
}

// ---------------------------------------------------------------------------
// gate = 2*sigmoid(x[:, :32] @ w_gate); v += gate[h] * ve   (one block per t)
// ---------------------------------------------------------------------------
__global__ __launch_bounds__(256) void gate_add(
    const float* __restrict__ x, const float* __restrict__ ve,
    const float* __restrict__ wg, bf16* __restrict__ vb)
{
    const int t = blockIdx.x;
    __shared__ float g[NH];
    if (threadIdx.x < NH) {
        float s = 0.f;
        #pragma unroll
        for (int c = 0; c < 32; ++c)
            s += x[(size_t)t*EMB + c] * wg[c*NH + threadIdx.x];
        g[threadIdx.x] = 2.f / (1.f + __expf(-s));
    }
    __syncthreads();
    for (int e = threadIdx.x; e < EMB; e += 256) {
        float v = b2f(vb[(size_t)t*EMB + e]);
        v += g[e >> 7] * ve[(size_t)t*EMB + e];
        vb[(size_t)t*EMB + e] = f2b(v);
    }
}

// ---------------------------------------------------------------------------
// RoPE + RMS-norm, in place on q/k bf16 buffers. one wave per (t, h, q|k)
// ---------------------------------------------------------------------------
__global__ __launch_bounds__(64) void rope_rms(
    bf16* __restrict__ qb, bf16* __restrict__ kb,
    const float* __restrict__ cosb, const float* __restrict__ sinb)
{
    const int t = blockIdx.x, h = blockIdx.y;
    bf16* base = (blockIdx.z ? kb : qb) + ((size_t)t*NH + h)*HD;
    const int d = threadIdx.x;           // 0..63
    float x1 = b2f(base[d]), x2 = b2f(base[d+HALF]);
    float c = cosb[t*HALF + d];
    float s = sinb[t*HALF + d];
    float y1 = x1*c + x2*s;
    float y2 = x2*c - x1*s;              // = x1*(-s) + x2*c
    float ss = y1*y1 + y2*y2;
    #pragma unroll
    for (int off = 32; off > 0; off >>= 1) ss += __shfl_down(ss, off);
    ss = __shfl(ss, 0);
    float r = rsqrtf(ss * (1.0f/HD) + 1e-6f);
    base[d]      = f2b(y1*r);
    base[d+HALF] = f2b(y2*r);
}

// ---------------------------------------------------------------------------
// Sliding-window causal attention. One 256-thread block per (query i, head h).
// Two-pass softmax with scores staged in LDS (window <= 1024).
// ---------------------------------------------------------------------------
__global__ __launch_bounds__(256) void attn_kernel(
    const bf16* __restrict__ qb, const bf16* __restrict__ kb,
    const bf16* __restrict__ vb, bf16* __restrict__ yb,
    const int* __restrict__ wptr)
{
    const int i = blockIdx.x, h = blockIdx.y;
    int W = *wptr;
    W = min(max(W, 1), 1024);            // robust to scalar encoding; LDS cap
    const int jlo = max(0, i - W + 1);
    const int nj = i - jlo + 1;          // <= 1024
    const int tid = threadIdx.x;
    __shared__ float qs[HD];
    __shared__ float p[1024];
    __shared__ float red[4];
    __shared__ float red2[4];
    __shared__ float part[256];
    if (tid < HD) qs[tid] = b2f(qb[((size_t)i*NH + h)*HD + tid]);
    __syncthreads();
    const float scale = 0.08838834764831845f;   // 1/sqrt(128)
    // phase 1: scores
    float lmax = -1e30f;
    for (int jj = tid; jj < nj; jj += 256) {
        const bf16* kr = kb + ((size_t)(jlo+jj)*NH + h)*HD;
        float s = 0.f;
        #pragma unroll 8
        for (int d = 0; d < HD; ++d) s += qs[d] * b2f(kr[d]);
        s *= scale;
        p[jj] = s;
        lmax = fmaxf(lmax, s);
    }
    #pragma unroll
    for (int off = 32; off > 0; off >>= 1) lmax = fmaxf(lmax, __shfl_down(lmax, off));
    if ((tid & 63) == 0) red[tid >> 6] = lmax;
    __syncthreads();
    const float m = fmaxf(fmaxf(red[0], red[1]), fmaxf(red[2], red[3]));
    // phase 2: exp + sum
    float lsum = 0.f;
    for (int jj = tid; jj < nj; jj += 256) {
        float e = __expf(p[jj] - m);
        p[jj] = e;
        lsum += e;
    }
    #pragma unroll
    for (int off = 32; off > 0; off >>= 1) lsum += __shfl_down(lsum, off);
    if ((tid & 63) == 0) red2[tid >> 6] = lsum;
    __syncthreads();   // also orders p[] exp-writes before PV reads
    const float denom = red2[0] + red2[1] + red2[2] + red2[3];
    // phase 3: PV — thread (d, half) accumulates every other key
    const int d  = tid & 127;
    const int hf = tid >> 7;
    float acc = 0.f;
    for (int jj = hf; jj < nj; jj += 2)
        acc += p[jj] * b2f(vb[((size_t)(jlo+jj)*NH + h)*HD + d]);
    part[tid] = acc;
    __syncthreads();
    if (tid < HD)
        yb[(size_t)i*EMB + h*HD + d] = f2b((part[d] + part[d+128]) / denom);
}

// ---------------------------------------------------------------------------
// Output projection: out[4096,1024] = y[4096,1024](bf16) @ w_proj(fp32), fp32 out
// ---------------------------------------------------------------------------
__global__ __launch_bounds__(256) void proj_gemm(
    const bf16* __restrict__ A, const float* __restrict__ Bw, float* __restrict__ out)
{
    const int m0 = blockIdx.y * 64;
    const int n0 = blockIdx.x * 64;
    __shared__ float As[16][65];
    __shared__ float Bs[16][65];
    const int tid = threadIdx.x;
    const int tx = tid & 15, ty = tid >> 4;
    float acc[4][4] = {};
    for (int k0 = 0; k0 < EMB; k0 += 16) {
        {
            int e = tid * 4;
            int m = e >> 4, kk = e & 15;
            const bf16* src = A + (size_t)(m0 + m) * EMB + k0 + kk;
            As[kk+0][m] = b2f(src[0]);
            As[kk+1][m] = b2f(src[1]);
            As[kk+2][m] = b2f(src[2]);
            As[kk+3][m] = b2f(src[3]);
        }
        {
            int e = tid * 4;
            int kk = e >> 6, n = e & 63;
            const float4 f = *(const float4*)(Bw + (size_t)(k0 + kk) * EMB + n0 + n);
            Bs[kk][n+0] = f.x; Bs[kk][n+1] = f.y; Bs[kk][n+2] = f.z; Bs[kk][n+3] = f.w;
        }
        __syncthreads();
        #pragma unroll
        for (int kk = 0; kk < 16; ++kk) {
            float a[4], b[4];
            #pragma unroll
            for (int i = 0; i < 4; ++i) a[i] = As[kk][ty*4+i];
            #pragma unroll
            for (int j = 0; j < 4; ++j) b[j] = Bs[kk][tx*4+j];
            #pragma unroll
            for (int i = 0; i < 4; ++i)
                #pragma unroll
                for (int j = 0; j < 4; ++j)
                    acc[i][j] += a[i] * b[j];
        }
        __syncthreads();
    }
    #pragma unroll
    for (int i = 0; i < 4; ++i)
        #pragma unroll
        for (int j = 0; j < 4; ++j)
            out[(size_t)(m0 + ty*4+i) * EMB + n0 + tx*4+j] = acc[i][j];
}

// ---------------------------------------------------------------------------
extern "C" void kernel_launch(void* const* d_in, const int* in_sizes, int n_in,
                              void* d_out, int out_size, void* d_ws, size_t ws_size,
                              hipStream_t stream)
{
    const float* x    = (const float*)d_in[0];
    const float* ve   = (const float*)d_in[1];
    const float* cosb = (const float*)d_in[2];
    const float* sinb = (const float*)d_in[3];
    const float* wq   = (const float*)d_in[4];
    const float* wk   = (const float*)d_in[5];
    const float* wv   = (const float*)d_in[6];
    const float* wg   = (const float*)d_in[7];
    const float* wp   = (const float*)d_in[8];
    const int*   wsz  = (const int*)d_in[9];
    float* out = (float*)d_out;

    bf16* qb = (bf16*)d_ws;                        // 4096x1024 bf16 (8 MB)
    bf16* kb = qb + (size_t)T_SEQ*EMB;
    bf16* vb = kb + (size_t)T_SEQ*EMB;
    bf16* yb = vb + (size_t)T_SEQ*EMB;             // 32 MB total

    dim3 g1(EMB/64, T_SEQ/64, 3);
    qkv_gemm<<<g1, 256, 0, stream>>>(x, wq, wk, wv, qb, kb, vb);
    gate_add<<<T_SEQ, 256, 0, stream>>>(x, ve, wg, vb);
    rope_rms<<<dim3(T_SEQ, NH, 2), 64, 0, stream>>>(qb, kb, cosb, sinb);
    attn_kernel<<<dim3(T_SEQ, NH), 256, 0, stream>>>(qb, kb, vb, yb, wsz);
    proj_gemm<<<dim3(EMB/64, T_SEQ/64), 256, 0, stream>>>(yb, wp, out);
}

// Round 4
// 862.932 us; speedup vs baseline: 3.4738x; 3.4738x over previous
//
#include <hip/hip_runtime.h>
#include <hip/hip_bf16.h>
#include <math.h>

#define T_SEQ 4096
#define EMB   1024
#define NH    8
#define HD    128
#define HALF  64

typedef __hip_bfloat16 bf16;
typedef __attribute__((ext_vector_type(8))) short short8;
typedef __attribute__((ext_vector_type(4))) short short4v;
typedef __attribute__((ext_vector_type(4))) float float4v;

static __device__ __forceinline__ float b2f(bf16 v) { return __bfloat162float(v); }
static __device__ __forceinline__ bf16  f2b(float v) { return __float2bfloat16(v); }
static __device__ __forceinline__ short f2bs(float v) {
    bf16 h = __float2bfloat16(v); short s; __builtin_memcpy(&s, &h, 2); return s;
}

// ---------------------------------------------------------------------------
// QKV projection: C[4096,1024] = x[4096,1024] @ W[1024,1024], z selects q/k/v
// fp32 inputs, 64x64 tile, BK=16, 256 threads, 4x4/thread, fp32 acc, bf16 out
// ---------------------------------------------------------------------------
__global__ __launch_bounds__(256) void qkv_gemm(
    const float* __restrict__ x,
    const float* __restrict__ wq, const float* __restrict__ wk, const float* __restrict__ wv,
    bf16* __restrict__ qb, bf16* __restrict__ kb, bf16* __restrict__ vb)
{
    const float* B = (blockIdx.z == 0) ? wq : (blockIdx.z == 1) ? wk : wv;
    bf16*        C = (blockIdx.z == 0) ? qb : (blockIdx.z == 1) ? kb : vb;
    const int m0 = blockIdx.y * 64;
    const int n0 = blockIdx.x * 64;
    __shared__ float As[16][65];
    __shared__ float Bs[16][65];
    const int tid = threadIdx.x;
    const int tx = tid & 15, ty = tid >> 4;
    float acc[4][4] = {};
    for (int k0 = 0; k0 < EMB; k0 += 16) {
        {
            int e = tid * 4;
            int m = e >> 4, kk = e & 15;
            const float4 f = *(const float4*)(x + (size_t)(m0 + m) * EMB + k0 + kk);
            As[kk+0][m] = f.x; As[kk+1][m] = f.y; As[kk+2][m] = f.z; As[kk+3][m] = f.w;
        }
        {
            int e = tid * 4;
            int kk = e >> 6, n = e & 63;
            const float4 f = *(const float4*)(B + (size_t)(k0 + kk) * EMB + n0 + n);
            Bs[kk][n+0] = f.x; Bs[kk][n+1] = f.y; Bs[kk][n+2] = f.z; Bs[kk][n+3] = f.w;
        }
        __syncthreads();
        #pragma unroll
        for (int kk = 0; kk < 16; ++kk) {
            float a[4], b[4];
            #pragma unroll
            for (int i = 0; i < 4; ++i) a[i] = As[kk][ty*4+i];
            #pragma unroll
            for (int j = 0; j < 4; ++j) b[j] = Bs[kk][tx*4+j];
            #pragma unroll
            for (int i = 0; i < 4; ++i)
                #pragma unroll
                for (int j = 0; j < 4; ++j)
                    acc[i][j] += a[i] * b[j];
        }
        __syncthreads();
    }
    #pragma unroll
    for (int i = 0; i < 4; ++i)
        #pragma unroll
        for (int j = 0; j < 4; ++j)
            C[(size_t)(m0 + ty*4+i) * EMB + n0 + tx*4+j] = f2b(acc[i][j]);
}

// ---------------------------------------------------------------------------
// gate = 2*sigmoid(x[:, :32] @ w_gate); v += gate[h] * ve   (one block per t)
// ---------------------------------------------------------------------------
__global__ __launch_bounds__(256) void gate_add(
    const float* __restrict__ x, const float* __restrict__ ve,
    const float* __restrict__ wg, bf16* __restrict__ vb)
{
    const int t = blockIdx.x;
    __shared__ float g[NH];
    if (threadIdx.x < NH) {
        float s = 0.f;
        #pragma unroll
        for (int c = 0; c < 32; ++c)
            s += x[(size_t)t*EMB + c] * wg[c*NH + threadIdx.x];
        g[threadIdx.x] = 2.f / (1.f + __expf(-s));
    }
    __syncthreads();
    for (int e = threadIdx.x; e < EMB; e += 256) {
        float v = b2f(vb[(size_t)t*EMB + e]);
        v += g[e >> 7] * ve[(size_t)t*EMB + e];
        vb[(size_t)t*EMB + e] = f2b(v);
    }
}

// ---------------------------------------------------------------------------
// RoPE + RMS-norm, in place on q/k bf16 buffers. one wave per (t, h, q|k)
// ---------------------------------------------------------------------------
__global__ __launch_bounds__(64) void rope_rms(
    bf16* __restrict__ qb, bf16* __restrict__ kb,
    const float* __restrict__ cosb, const float* __restrict__ sinb)
{
    const int t = blockIdx.x, h = blockIdx.y;
    bf16* base = (blockIdx.z ? kb : qb) + ((size_t)t*NH + h)*HD;
    const int d = threadIdx.x;           // 0..63
    float x1 = b2f(base[d]), x2 = b2f(base[d+HALF]);
    float c = cosb[t*HALF + d];
    float s = sinb[t*HALF + d];
    float y1 = x1*c + x2*s;
    float y2 = x2*c - x1*s;
    float ss = y1*y1 + y2*y2;
    #pragma unroll
    for (int off = 32; off > 0; off >>= 1) ss += __shfl_down(ss, off);
    ss = __shfl(ss, 0);
    float r = rsqrtf(ss * (1.0f/HD) + 1e-6f);
    base[d]      = f2b(y1*r);
    base[d+HALF] = f2b(y2*r);
}

// ---------------------------------------------------------------------------
// V transpose: vt[h][d][t] <- vb[t][h*128+d]. 64x64 tiles via LDS.
// ---------------------------------------------------------------------------
__global__ __launch_bounds__(256) void transpose_v(
    const bf16* __restrict__ vbh, bf16* __restrict__ vth)
{
    const short* vb = (const short*)vbh;
    short* vt = (short*)vth;
    __shared__ short tile[64][68];
    const int t0 = blockIdx.x * 64;
    const int d0 = blockIdx.y * 64;
    const int h  = blockIdx.z;
    const int tid = threadIdx.x;
    #pragma unroll
    for (int k = 0; k < 4; ++k) {
        int id = tid + k*256;
        int r = id >> 4, cg = id & 15;
        short4v vrow = *(const short4v*)(vb + (size_t)(t0+r)*EMB + h*HD + d0 + cg*4);
        *(short4v*)&tile[r][cg*4] = vrow;
    }
    __syncthreads();
    #pragma unroll
    for (int k = 0; k < 4; ++k) {
        int id = tid + k*256;
        int dr = id >> 4, tg = id & 15;
        short4v w;
        #pragma unroll
        for (int j = 0; j < 4; ++j) w[j] = tile[tg*4+j][dr];
        *(short4v*)(vt + (size_t)(h*HD + d0 + dr)*T_SEQ + t0 + tg*4) = w;
    }
}

// ---------------------------------------------------------------------------
// Flash attention, MFMA 16x16x32 bf16. One block = 64 queries x 1 head.
// 4 waves; wave w owns query rows w*16..w*16+15 and the full D=128 output.
// K tile (64x128) and V^T tile (128x64) staged in LDS; online softmax.
// Fragment layouts per m89/m120: C/D col=lane&15,row=quad*4+reg;
// A m=lane&15,k=quad*8+j; B n=lane&15,k=quad*8+j.
// ---------------------------------------------------------------------------
__global__ __launch_bounds__(256) void attn_flash(
    const bf16* __restrict__ qbh, const bf16* __restrict__ kbh,
    const bf16* __restrict__ vth, bf16* __restrict__ ybh,
    const int* __restrict__ wptr)
{
    const short* qb = (const short*)qbh;
    const short* kb = (const short*)kbh;
    const short* vt = (const short*)vth;
    short* yb = (short*)ybh;

    __shared__ short Ks[64*136];    // [key][dim], rows padded 128->136
    __shared__ short Vs[128*72];    // [dim][key], rows padded 64->72
    __shared__ short Ps[4*16*72];   // per-wave P strip, rows padded 64->72

    int W = *wptr; W = min(max(W, 1), 1024);
    const int i0 = blockIdx.x * 64;
    const int h  = blockIdx.y;
    const int tid  = threadIdx.x;
    const int wv   = tid >> 6;
    const int lane = tid & 63;
    const int cl   = lane & 15;
    const int q    = lane >> 4;
    const int m0   = wv * 16;
    const float scale = 0.08838834764831845f;   // 1/sqrt(128)

    // Q strip A-fragments in registers for the whole kernel
    short8 qa[4];
    {
        const short* qbase = qb + (size_t)(i0 + m0 + cl) * EMB + h*HD + q*8;
        #pragma unroll
        for (int ks = 0; ks < 4; ++ks)
            qa[ks] = *(const short8*)(qbase + ks*32);
    }

    float4v o[8];
    #pragma unroll
    for (int n = 0; n < 8; ++n) o[n] = (float4v){0.f,0.f,0.f,0.f};
    float mrow[4] = {-1e30f,-1e30f,-1e30f,-1e30f};
    float lrow[4] = {0.f,0.f,0.f,0.f};

    const int lo_key  = i0 - W + 1;
    const int jt_start = lo_key > 0 ? (lo_key >> 6) : 0;
    const int jt_end   = i0 >> 6;

    for (int jt = jt_start; jt <= jt_end; ++jt) {
        const int j0 = jt << 6;
        __syncthreads();
        // cooperative staging: K tile and V^T tile, 16B chunks
        #pragma unroll
        for (int kk = 0; kk < 4; ++kk) {
            int cid = tid + kk*256;
            int key = cid >> 4, c16 = cid & 15;
            short8 kd = *(const short8*)(kb + (size_t)(j0+key)*EMB + h*HD + c16*8);
            *(short8*)&Ks[key*136 + c16*8] = kd;
            int d = cid >> 3, c8 = cid & 7;
            short8 vd = *(const short8*)(vt + (size_t)(h*HD + d)*T_SEQ + j0 + c8*8);
            *(short8*)&Vs[d*72 + c8*8] = vd;
        }
        __syncthreads();

        // S = Q K^T : 16x64 per wave as 4 N-subtiles
        float4v s[4];
        #pragma unroll
        for (int nt = 0; nt < 4; ++nt) {
            s[nt] = (float4v){0.f,0.f,0.f,0.f};
            #pragma unroll
            for (int ks = 0; ks < 4; ++ks) {
                short8 kf = *(const short8*)&Ks[(nt*16 + cl)*136 + ks*32 + q*8];
                s[nt] = __builtin_amdgcn_mfma_f32_16x16x32_bf16(qa[ks], kf, s[nt], 0, 0, 0);
            }
        }
        // scale + (boundary tiles only) mask
        const bool needmask = (j0 + 63 > i0) || (j0 < i0 + 64 - W);
        #pragma unroll
        for (int nt = 0; nt < 4; ++nt) {
            #pragma unroll
            for (int r = 0; r < 4; ++r) {
                float sv = s[nt][r] * scale;
                if (needmask) {
                    int j    = j0 + nt*16 + cl;
                    int irow = i0 + m0 + q*4 + r;
                    if (j > irow || j <= irow - W) sv = -1e30f;
                }
                s[nt][r] = sv;
            }
        }
        // online softmax (rows live in C-layout: reg r = row q*4+r, 16 lanes/row)
        float alpha[4];
        #pragma unroll
        for (int r = 0; r < 4; ++r) {
            float rm = fmaxf(fmaxf(s[0][r], s[1][r]), fmaxf(s[2][r], s[3][r]));
            rm = fmaxf(rm, __shfl_xor(rm, 1));
            rm = fmaxf(rm, __shfl_xor(rm, 2));
            rm = fmaxf(rm, __shfl_xor(rm, 4));
            rm = fmaxf(rm, __shfl_xor(rm, 8));
            float mnew = fmaxf(mrow[r], rm);
            alpha[r] = __expf(mrow[r] - mnew);
            mrow[r] = mnew;
            float rs = 0.f;
            #pragma unroll
            for (int nt = 0; nt < 4; ++nt) {
                float p = __expf(s[nt][r] - mnew);
                s[nt][r] = p;
                rs += p;
            }
            rs += __shfl_xor(rs, 1);
            rs += __shfl_xor(rs, 2);
            rs += __shfl_xor(rs, 4);
            rs += __shfl_xor(rs, 8);
            lrow[r] = lrow[r]*alpha[r] + rs;
        }
        // rescale O accumulator
        #pragma unroll
        for (int n = 0; n < 8; ++n)
            #pragma unroll
            for (int r = 0; r < 4; ++r)
                o[n][r] *= alpha[r];
        // P: C-layout regs -> bf16 LDS (per-wave strip)
        #pragma unroll
        for (int nt = 0; nt < 4; ++nt)
            #pragma unroll
            for (int r = 0; r < 4; ++r)
                Ps[wv*1152 + (q*4+r)*72 + nt*16 + cl] = f2bs(s[nt][r]);
        // P A-fragments (same-wave LDS dependency; compiler orders via lgkmcnt)
        short8 pa[2];
        #pragma unroll
        for (int k2 = 0; k2 < 2; ++k2)
            pa[k2] = *(const short8*)&Ps[wv*1152 + cl*72 + k2*32 + q*8];
        // O += P V
        #pragma unroll
        for (int n = 0; n < 8; ++n) {
            #pragma unroll
            for (int k2 = 0; k2 < 2; ++k2) {
                short8 vf = *(const short8*)&Vs[(n*16 + cl)*72 + k2*32 + q*8];
                o[n] = __builtin_amdgcn_mfma_f32_16x16x32_bf16(pa[k2], vf, o[n], 0, 0, 0);
            }
        }
    }
    // epilogue: O / l -> yb
    #pragma unroll
    for (int r = 0; r < 4; ++r) {
        float inv = 1.f / lrow[r];
        int row = i0 + m0 + q*4 + r;
        #pragma unroll
        for (int n = 0; n < 8; ++n)
            yb[(size_t)row*EMB + h*HD + n*16 + cl] = f2bs(o[n][r] * inv);
    }
}

// ---------------------------------------------------------------------------
// Output projection: out[4096,1024] = y[4096,1024](bf16) @ w_proj(fp32), fp32 out
// ---------------------------------------------------------------------------
__global__ __launch_bounds__(256) void proj_gemm(
    const bf16* __restrict__ A, const float* __restrict__ Bw, float* __restrict__ out)
{
    const int m0 = blockIdx.y * 64;
    const int n0 = blockIdx.x * 64;
    __shared__ float As[16][65];
    __shared__ float Bs[16][65];
    const int tid = threadIdx.x;
    const int tx = tid & 15, ty = tid >> 4;
    float acc[4][4] = {};
    for (int k0 = 0; k0 < EMB; k0 += 16) {
        {
            int e = tid * 4;
            int m = e >> 4, kk = e & 15;
            const bf16* src = A + (size_t)(m0 + m) * EMB + k0 + kk;
            As[kk+0][m] = b2f(src[0]);
            As[kk+1][m] = b2f(src[1]);
            As[kk+2][m] = b2f(src[2]);
            As[kk+3][m] = b2f(src[3]);
        }
        {
            int e = tid * 4;
            int kk = e >> 6, n = e & 63;
            const float4 f = *(const float4*)(Bw + (size_t)(k0 + kk) * EMB + n0 + n);
            Bs[kk][n+0] = f.x; Bs[kk][n+1] = f.y; Bs[kk][n+2] = f.z; Bs[kk][n+3] = f.w;
        }
        __syncthreads();
        #pragma unroll
        for (int kk = 0; kk < 16; ++kk) {
            float a[4], b[4];
            #pragma unroll
            for (int i = 0; i < 4; ++i) a[i] = As[kk][ty*4+i];
            #pragma unroll
            for (int j = 0; j < 4; ++j) b[j] = Bs[kk][tx*4+j];
            #pragma unroll
            for (int i = 0; i < 4; ++i)
                #pragma unroll
                for (int j = 0; j < 4; ++j)
                    acc[i][j] += a[i] * b[j];
        }
        __syncthreads();
    }
    #pragma unroll
    for (int i = 0; i < 4; ++i)
        #pragma unroll
        for (int j = 0; j < 4; ++j)
            out[(size_t)(m0 + ty*4+i) * EMB + n0 + tx*4+j] = acc[i][j];
}

// ---------------------------------------------------------------------------
extern "C" void kernel_launch(void* const* d_in, const int* in_sizes, int n_in,
                              void* d_out, int out_size, void* d_ws, size_t ws_size,
                              hipStream_t stream)
{
    const float* x    = (const float*)d_in[0];
    const float* ve   = (const float*)d_in[1];
    const float* cosb = (const float*)d_in[2];
    const float* sinb = (const float*)d_in[3];
    const float* wq   = (const float*)d_in[4];
    const float* wk   = (const float*)d_in[5];
    const float* wv   = (const float*)d_in[6];
    const float* wg   = (const float*)d_in[7];
    const float* wp   = (const float*)d_in[8];
    const int*   wsz  = (const int*)d_in[9];
    float* out = (float*)d_out;

    bf16* qb = (bf16*)d_ws;                        // 8 MB each
    bf16* kb = qb + (size_t)T_SEQ*EMB;
    bf16* vb = kb + (size_t)T_SEQ*EMB;
    bf16* vt = vb + (size_t)T_SEQ*EMB;             // v transposed [h][d][t]
    bf16* yb = vb;                                 // vb dead after transpose; alias

    dim3 g1(EMB/64, T_SEQ/64, 3);
    qkv_gemm<<<g1, 256, 0, stream>>>(x, wq, wk, wv, qb, kb, vb);
    gate_add<<<T_SEQ, 256, 0, stream>>>(x, ve, wg, vb);
    rope_rms<<<dim3(T_SEQ, NH, 2), 64, 0, stream>>>(qb, kb, cosb, sinb);
    transpose_v<<<dim3(T_SEQ/64, HD/64, NH), 256, 0, stream>>>(vb, vt);
    attn_flash<<<dim3(T_SEQ/64, NH), 256, 0, stream>>>(qb, kb, vt, yb, wsz);
    proj_gemm<<<dim3(EMB/64, T_SEQ/64), 256, 0, stream>>>(yb, wp, out);
}

// Round 5
// 279.320 us; speedup vs baseline: 10.7321x; 3.0894x over previous
//
#include <hip/hip_runtime.h>
#include <hip/hip_bf16.h>
#include <math.h>

#define T_SEQ 4096
#define EMB   1024
#define NH    8
#define HD    128
#define HALF  64

typedef __hip_bfloat16 bf16;
typedef __attribute__((ext_vector_type(8))) short short8;
typedef __attribute__((ext_vector_type(4))) short short4v;
typedef __attribute__((ext_vector_type(4))) float float4v;

static __device__ __forceinline__ float b2f(bf16 v) { return __bfloat162float(v); }
static __device__ __forceinline__ bf16  f2b(float v) { return __float2bfloat16(v); }
static __device__ __forceinline__ short f2bs(float v) {
    bf16 h = __float2bfloat16(v); short s; __builtin_memcpy(&s, &h, 2); return s;
}
// async global->LDS, 16B per lane; lds base must be wave-uniform
static __device__ __forceinline__ void gload16(const short* g, short* l) {
    __builtin_amdgcn_global_load_lds((__attribute__((address_space(1))) void*)g,
                                     (__attribute__((address_space(3))) void*)l, 16, 0, 0);
}

// ---------------------------------------------------------------------------
// fp32 -> bf16 straight convert (x)
// ---------------------------------------------------------------------------
__global__ __launch_bounds__(256) void convert_x(
    const float* __restrict__ src, short* __restrict__ dst)
{
    int i = (blockIdx.x * 256 + threadIdx.x) * 4;
    float4 f = *(const float4*)(src + i);
    short4v s = { f2bs(f.x), f2bs(f.y), f2bs(f.z), f2bs(f.w) };
    *(short4v*)(dst + i) = s;
}

// ---------------------------------------------------------------------------
// Weight convert + transpose: W[k][n] fp32 -> wbT[z][n][k] bf16 (z = wq,wk,wv,wp)
// ---------------------------------------------------------------------------
__global__ __launch_bounds__(256) void convert_wT(
    const float* __restrict__ w0, const float* __restrict__ w1,
    const float* __restrict__ w2, const float* __restrict__ w3,
    short* __restrict__ wbT)
{
    const float* W = (blockIdx.z==0)?w0:(blockIdx.z==1)?w1:(blockIdx.z==2)?w2:w3;
    short* dst = wbT + (size_t)blockIdx.z * EMB * EMB;
    __shared__ float tile[64][65];
    const int k0 = blockIdx.x * 64;
    const int n0 = blockIdx.y * 64;
    const int tid = threadIdx.x;
    #pragma unroll
    for (int t = 0; t < 4; ++t) {
        int id = tid + t*256;
        int r = id >> 4, c4 = id & 15;
        float4 f = *(const float4*)(W + (size_t)(k0+r)*EMB + n0 + c4*4);
        tile[r][c4*4+0]=f.x; tile[r][c4*4+1]=f.y; tile[r][c4*4+2]=f.z; tile[r][c4*4+3]=f.w;
    }
    __syncthreads();
    #pragma unroll
    for (int t = 0; t < 4; ++t) {
        int id = tid + t*256;
        int n = id >> 4, k4 = id & 15;
        short4v s;
        #pragma unroll
        for (int j = 0; j < 4; ++j) s[j] = f2bs(tile[k4*4+j][n]);
        *(short4v*)(dst + (size_t)(n0+n)*EMB + k0 + k4*4) = s;
    }
}

// ---------------------------------------------------------------------------
// MFMA GEMM (m97 structure): C[4096, 3072] = xb @ wbT^T, split to q/k/v.
// 128x128 tile, BK=32, 4 waves each owning a 64x64 quadrant (4x4 MFMA grid).
// ---------------------------------------------------------------------------
__global__ __launch_bounds__(256) void qkv_gemm_mfma(
    const short* __restrict__ xb, const short* __restrict__ wbT,
    short* __restrict__ qb, short* __restrict__ kb, short* __restrict__ vb)
{
    __shared__ short As[128*32];
    __shared__ short Bs[128*32];
    const int n0g = blockIdx.x * 128;          // 0..3071
    const int m0  = blockIdx.y * 128;
    const int z   = n0g >> 10;
    short* C = (z==0)?qb:(z==1)?kb:vb;
    const int ncol0 = n0g & 1023;
    const int tid = threadIdx.x;
    const int wv = tid >> 6, lane = tid & 63;
    const int cl = lane & 15, q = lane >> 4;
    const int wm = wv >> 1, wn = wv & 1;
    const int lrow = lane >> 2;
    const int lcol = (lane & 3) * 8;
    float4v acc[4][4];
    #pragma unroll
    for (int mi=0;mi<4;++mi)
        #pragma unroll
        for (int ni=0;ni<4;++ni) acc[mi][ni]=(float4v){0.f,0.f,0.f,0.f};

    for (int k0 = 0; k0 < EMB; k0 += 32) {
        __syncthreads();
        #pragma unroll
        for (int t = 0; t < 2; ++t) {
            int chunk = wv*2 + t;
            gload16(xb  + (size_t)(m0  + chunk*16 + lrow)*EMB + k0 + lcol, &As[chunk*512]);
            gload16(wbT + (size_t)(n0g + chunk*16 + lrow)*EMB + k0 + lcol, &Bs[chunk*512]);
        }
        __syncthreads();
        short8 af[4], bfr[4];
        #pragma unroll
        for (int mi=0;mi<4;++mi) af[mi]  = *(const short8*)&As[(wm*64+mi*16+cl)*32 + q*8];
        #pragma unroll
        for (int ni=0;ni<4;++ni) bfr[ni] = *(const short8*)&Bs[(wn*64+ni*16+cl)*32 + q*8];
        #pragma unroll
        for (int mi=0;mi<4;++mi)
            #pragma unroll
            for (int ni=0;ni<4;++ni)
                acc[mi][ni] = __builtin_amdgcn_mfma_f32_16x16x32_bf16(af[mi], bfr[ni], acc[mi][ni], 0, 0, 0);
    }
    #pragma unroll
    for (int mi=0;mi<4;++mi)
        #pragma unroll
        for (int ni=0;ni<4;++ni)
            #pragma unroll
            for (int r=0;r<4;++r)
                C[(size_t)(m0+wm*64+mi*16+q*4+r)*EMB + ncol0 + wn*64+ni*16+cl] = f2bs(acc[mi][ni][r]);
}

// ---------------------------------------------------------------------------
// MFMA GEMM: out[4096,1024] fp32 = yb(bf16) @ wpT^T
// ---------------------------------------------------------------------------
__global__ __launch_bounds__(256) void proj_gemm_mfma(
    const short* __restrict__ yb, const short* __restrict__ wpT,
    float* __restrict__ out)
{
    __shared__ short As[128*32];
    __shared__ short Bs[128*32];
    const int n0 = blockIdx.x * 128;
    const int m0 = blockIdx.y * 128;
    const int tid = threadIdx.x;
    const int wv = tid >> 6, lane = tid & 63;
    const int cl = lane & 15, q = lane >> 4;
    const int wm = wv >> 1, wn = wv & 1;
    const int lrow = lane >> 2;
    const int lcol = (lane & 3) * 8;
    float4v acc[4][4];
    #pragma unroll
    for (int mi=0;mi<4;++mi)
        #pragma unroll
        for (int ni=0;ni<4;++ni) acc[mi][ni]=(float4v){0.f,0.f,0.f,0.f};

    for (int k0 = 0; k0 < EMB; k0 += 32) {
        __syncthreads();
        #pragma unroll
        for (int t = 0; t < 2; ++t) {
            int chunk = wv*2 + t;
            gload16(yb  + (size_t)(m0 + chunk*16 + lrow)*EMB + k0 + lcol, &As[chunk*512]);
            gload16(wpT + (size_t)(n0 + chunk*16 + lrow)*EMB + k0 + lcol, &Bs[chunk*512]);
        }
        __syncthreads();
        short8 af[4], bfr[4];
        #pragma unroll
        for (int mi=0;mi<4;++mi) af[mi]  = *(const short8*)&As[(wm*64+mi*16+cl)*32 + q*8];
        #pragma unroll
        for (int ni=0;ni<4;++ni) bfr[ni] = *(const short8*)&Bs[(wn*64+ni*16+cl)*32 + q*8];
        #pragma unroll
        for (int mi=0;mi<4;++mi)
            #pragma unroll
            for (int ni=0;ni<4;++ni)
                acc[mi][ni] = __builtin_amdgcn_mfma_f32_16x16x32_bf16(af[mi], bfr[ni], acc[mi][ni], 0, 0, 0);
    }
    #pragma unroll
    for (int mi=0;mi<4;++mi)
        #pragma unroll
        for (int ni=0;ni<4;++ni)
            #pragma unroll
            for (int r=0;r<4;++r)
                out[(size_t)(m0+wm*64+mi*16+q*4+r)*EMB + n0 + wn*64+ni*16+cl] = acc[mi][ni][r];
}

// ---------------------------------------------------------------------------
// gate = 2*sigmoid(x[:, :32] @ w_gate); v += gate[h] * ve   (one block per t)
// ---------------------------------------------------------------------------
__global__ __launch_bounds__(256) void gate_add(
    const float* __restrict__ x, const float* __restrict__ ve,
    const float* __restrict__ wg, bf16* __restrict__ vb)
{
    const int t = blockIdx.x;
    __shared__ float g[NH];
    if (threadIdx.x < NH) {
        float s = 0.f;
        #pragma unroll
        for (int c = 0; c < 32; ++c)
            s += x[(size_t)t*EMB + c] * wg[c*NH + threadIdx.x];
        g[threadIdx.x] = 2.f / (1.f + __expf(-s));
    }
    __syncthreads();
    for (int e = threadIdx.x; e < EMB; e += 256) {
        float v = b2f(vb[(size_t)t*EMB + e]);
        v += g[e >> 7] * ve[(size_t)t*EMB + e];
        vb[(size_t)t*EMB + e] = f2b(v);
    }
}

// ---------------------------------------------------------------------------
// RoPE + RMS-norm, in place on q/k bf16 buffers. one wave per (t, h, q|k)
// ---------------------------------------------------------------------------
__global__ __launch_bounds__(64) void rope_rms(
    bf16* __restrict__ qb, bf16* __restrict__ kb,
    const float* __restrict__ cosb, const float* __restrict__ sinb)
{
    const int t = blockIdx.x, h = blockIdx.y;
    bf16* base = (blockIdx.z ? kb : qb) + ((size_t)t*NH + h)*HD;
    const int d = threadIdx.x;
    float x1 = b2f(base[d]), x2 = b2f(base[d+HALF]);
    float c = cosb[t*HALF + d];
    float s = sinb[t*HALF + d];
    float y1 = x1*c + x2*s;
    float y2 = x2*c - x1*s;
    float ss = y1*y1 + y2*y2;
    #pragma unroll
    for (int off = 32; off > 0; off >>= 1) ss += __shfl_down(ss, off);
    ss = __shfl(ss, 0);
    float r = rsqrtf(ss * (1.0f/HD) + 1e-6f);
    base[d]      = f2b(y1*r);
    base[d+HALF] = f2b(y2*r);
}

// ---------------------------------------------------------------------------
// V transpose: vt[h][d][t] <- vb[t][h*128+d]. 64x64 tiles via LDS.
// ---------------------------------------------------------------------------
__global__ __launch_bounds__(256) void transpose_v(
    const bf16* __restrict__ vbh, bf16* __restrict__ vth)
{
    const short* vb = (const short*)vbh;
    short* vt = (short*)vth;
    __shared__ short tile[64][68];
    const int t0 = blockIdx.x * 64;
    const int d0 = blockIdx.y * 64;
    const int h  = blockIdx.z;
    const int tid = threadIdx.x;
    #pragma unroll
    for (int k = 0; k < 4; ++k) {
        int id = tid + k*256;
        int r = id >> 4, cg = id & 15;
        short4v vrow = *(const short4v*)(vb + (size_t)(t0+r)*EMB + h*HD + d0 + cg*4);
        *(short4v*)&tile[r][cg*4] = vrow;
    }
    __syncthreads();
    #pragma unroll
    for (int k = 0; k < 4; ++k) {
        int id = tid + k*256;
        int dr = id >> 4, tg = id & 15;
        short4v w;
        #pragma unroll
        for (int j = 0; j < 4; ++j) w[j] = tile[tg*4+j][dr];
        *(short4v*)(vt + (size_t)(h*HD + d0 + dr)*T_SEQ + t0 + tg*4) = w;
    }
}

// ---------------------------------------------------------------------------
// Flash attention, MFMA 16x16x32 bf16. One block = 64 queries x 1 head.
// ---------------------------------------------------------------------------
__global__ __launch_bounds__(256) void attn_flash(
    const bf16* __restrict__ qbh, const bf16* __restrict__ kbh,
    const bf16* __restrict__ vth, bf16* __restrict__ ybh,
    const int* __restrict__ wptr)
{
    const short* qb = (const short*)qbh;
    const short* kb = (const short*)kbh;
    const short* vt = (const short*)vth;
    short* yb = (short*)ybh;

    __shared__ short Ks[64*136];
    __shared__ short Vs[128*72];
    __shared__ short Ps[4*16*72];

    int W = *wptr; W = min(max(W, 1), 1024);
    const int i0 = blockIdx.x * 64;
    const int h  = blockIdx.y;
    const int tid  = threadIdx.x;
    const int wv   = tid >> 6;
    const int lane = tid & 63;
    const int cl   = lane & 15;
    const int q    = lane >> 4;
    const int m0   = wv * 16;
    const float scale = 0.08838834764831845f;

    short8 qa[4];
    {
        const short* qbase = qb + (size_t)(i0 + m0 + cl) * EMB + h*HD + q*8;
        #pragma unroll
        for (int ks = 0; ks < 4; ++ks)
            qa[ks] = *(const short8*)(qbase + ks*32);
    }

    float4v o[8];
    #pragma unroll
    for (int n = 0; n < 8; ++n) o[n] = (float4v){0.f,0.f,0.f,0.f};
    float mrow[4] = {-1e30f,-1e30f,-1e30f,-1e30f};
    float lrow[4] = {0.f,0.f,0.f,0.f};

    const int lo_key  = i0 - W + 1;
    const int jt_start = lo_key > 0 ? (lo_key >> 6) : 0;
    const int jt_end   = i0 >> 6;

    for (int jt = jt_start; jt <= jt_end; ++jt) {
        const int j0 = jt << 6;
        __syncthreads();
        #pragma unroll
        for (int kk = 0; kk < 4; ++kk) {
            int cid = tid + kk*256;
            int key = cid >> 4, c16 = cid & 15;
            short8 kd = *(const short8*)(kb + (size_t)(j0+key)*EMB + h*HD + c16*8);
            *(short8*)&Ks[key*136 + c16*8] = kd;
            int d = cid >> 3, c8 = cid & 7;
            short8 vd = *(const short8*)(vt + (size_t)(h*HD + d)*T_SEQ + j0 + c8*8);
            *(short8*)&Vs[d*72 + c8*8] = vd;
        }
        __syncthreads();

        float4v s[4];
        #pragma unroll
        for (int nt = 0; nt < 4; ++nt) {
            s[nt] = (float4v){0.f,0.f,0.f,0.f};
            #pragma unroll
            for (int ks = 0; ks < 4; ++ks) {
                short8 kf = *(const short8*)&Ks[(nt*16 + cl)*136 + ks*32 + q*8];
                s[nt] = __builtin_amdgcn_mfma_f32_16x16x32_bf16(qa[ks], kf, s[nt], 0, 0, 0);
            }
        }
        const bool needmask = (j0 + 63 > i0) || (j0 < i0 + 64 - W);
        #pragma unroll
        for (int nt = 0; nt < 4; ++nt) {
            #pragma unroll
            for (int r = 0; r < 4; ++r) {
                float sv = s[nt][r] * scale;
                if (needmask) {
                    int j    = j0 + nt*16 + cl;
                    int irow = i0 + m0 + q*4 + r;
                    if (j > irow || j <= irow - W) sv = -1e30f;
                }
                s[nt][r] = sv;
            }
        }
        float alpha[4];
        #pragma unroll
        for (int r = 0; r < 4; ++r) {
            float rm = fmaxf(fmaxf(s[0][r], s[1][r]), fmaxf(s[2][r], s[3][r]));
            rm = fmaxf(rm, __shfl_xor(rm, 1));
            rm = fmaxf(rm, __shfl_xor(rm, 2));
            rm = fmaxf(rm, __shfl_xor(rm, 4));
            rm = fmaxf(rm, __shfl_xor(rm, 8));
            float mnew = fmaxf(mrow[r], rm);
            alpha[r] = __expf(mrow[r] - mnew);
            mrow[r] = mnew;
            float rs = 0.f;
            #pragma unroll
            for (int nt = 0; nt < 4; ++nt) {
                float p = __expf(s[nt][r] - mnew);
                s[nt][r] = p;
                rs += p;
            }
            rs += __shfl_xor(rs, 1);
            rs += __shfl_xor(rs, 2);
            rs += __shfl_xor(rs, 4);
            rs += __shfl_xor(rs, 8);
            lrow[r] = lrow[r]*alpha[r] + rs;
        }
        #pragma unroll
        for (int n = 0; n < 8; ++n)
            #pragma unroll
            for (int r = 0; r < 4; ++r)
                o[n][r] *= alpha[r];
        #pragma unroll
        for (int nt = 0; nt < 4; ++nt)
            #pragma unroll
            for (int r = 0; r < 4; ++r)
                Ps[wv*1152 + (q*4+r)*72 + nt*16 + cl] = f2bs(s[nt][r]);
        short8 pa[2];
        #pragma unroll
        for (int k2 = 0; k2 < 2; ++k2)
            pa[k2] = *(const short8*)&Ps[wv*1152 + cl*72 + k2*32 + q*8];
        #pragma unroll
        for (int n = 0; n < 8; ++n) {
            #pragma unroll
            for (int k2 = 0; k2 < 2; ++k2) {
                short8 vf = *(const short8*)&Vs[(n*16 + cl)*72 + k2*32 + q*8];
                o[n] = __builtin_amdgcn_mfma_f32_16x16x32_bf16(pa[k2], vf, o[n], 0, 0, 0);
            }
        }
    }
    #pragma unroll
    for (int r = 0; r < 4; ++r) {
        float inv = 1.f / lrow[r];
        int row = i0 + m0 + q*4 + r;
        #pragma unroll
        for (int n = 0; n < 8; ++n)
            yb[(size_t)row*EMB + h*HD + n*16 + cl] = f2bs(o[n][r] * inv);
    }
}

// ---------------------------------------------------------------------------
extern "C" void kernel_launch(void* const* d_in, const int* in_sizes, int n_in,
                              void* d_out, int out_size, void* d_ws, size_t ws_size,
                              hipStream_t stream)
{
    const float* x    = (const float*)d_in[0];
    const float* ve   = (const float*)d_in[1];
    const float* cosb = (const float*)d_in[2];
    const float* sinb = (const float*)d_in[3];
    const float* wq   = (const float*)d_in[4];
    const float* wk   = (const float*)d_in[5];
    const float* wv   = (const float*)d_in[6];
    const float* wg   = (const float*)d_in[7];
    const float* wp   = (const float*)d_in[8];
    const int*   wsz  = (const int*)d_in[9];
    float* out = (float*)d_out;

    const size_t SEG = (size_t)T_SEQ * EMB;        // 4M elements = 8 MB bf16
    short* xb  = (short*)d_ws;                     // later reused as vt
    short* wbT = xb + SEG;                         // [4096][1024]: wq|wk|wv|wp transposed
    short* qb  = wbT + SEG;
    short* kb  = qb + SEG;
    short* vb  = kb + SEG;                         // 40 MB total
    short* vt  = xb;                               // alias: xb dead after qkv gemm
    short* yb  = vb;                               // alias: vb dead after transpose_v

    convert_x<<<T_SEQ*EMB/1024, 256, 0, stream>>>(x, xb);
    convert_wT<<<dim3(16, 16, 4), 256, 0, stream>>>(wq, wk, wv, wp, wbT);
    qkv_gemm_mfma<<<dim3(24, 32), 256, 0, stream>>>(xb, wbT, qb, kb, vb);
    gate_add<<<T_SEQ, 256, 0, stream>>>(x, ve, wg, (bf16*)vb);
    rope_rms<<<dim3(T_SEQ, NH, 2), 64, 0, stream>>>((bf16*)qb, (bf16*)kb, cosb, sinb);
    transpose_v<<<dim3(T_SEQ/64, HD/64, NH), 256, 0, stream>>>((bf16*)vb, (bf16*)vt);
    attn_flash<<<dim3(T_SEQ/64, NH), 256, 0, stream>>>((bf16*)qb, (bf16*)kb, (bf16*)vt, (bf16*)yb, wsz);
    proj_gemm_mfma<<<dim3(8, 32), 256, 0, stream>>>(yb, wbT + 3*SEG/4*0 + (size_t)3*EMB*EMB, out);
}

// Round 6
// 220.460 us; speedup vs baseline: 13.5974x; 1.2670x over previous
//
#include <hip/hip_runtime.h>
#include <hip/hip_bf16.h>
#include <math.h>

#define T_SEQ 4096
#define EMB   1024
#define NH    8
#define HD    128
#define HALF  64

typedef __hip_bfloat16 bf16;
typedef __attribute__((ext_vector_type(8))) short short8;
typedef __attribute__((ext_vector_type(4))) short short4v;
typedef __attribute__((ext_vector_type(4))) float float4v;

static __device__ __forceinline__ float b2f(bf16 v) { return __bfloat162float(v); }
static __device__ __forceinline__ bf16  f2b(float v) { return __float2bfloat16(v); }
static __device__ __forceinline__ short f2bs(float v) {
    bf16 h = __float2bfloat16(v); short s; __builtin_memcpy(&s, &h, 2); return s;
}
static __device__ __forceinline__ float bs2f(short s) {
    bf16 h; __builtin_memcpy(&h, &s, 2); return __bfloat162float(h);
}
// async global->LDS, 16B per lane; lds base must be wave-uniform
static __device__ __forceinline__ void gload16(const short* g, short* l) {
    __builtin_amdgcn_global_load_lds((__attribute__((address_space(1))) void*)g,
                                     (__attribute__((address_space(3))) void*)l, 16, 0, 0);
}

// ---------------------------------------------------------------------------
// fp32 -> bf16 straight convert (x)
// ---------------------------------------------------------------------------
__global__ __launch_bounds__(256) void convert_x(
    const float* __restrict__ src, short* __restrict__ dst)
{
    int i = (blockIdx.x * 256 + threadIdx.x) * 4;
    float4 f = *(const float4*)(src + i);
    short4v s = { f2bs(f.x), f2bs(f.y), f2bs(f.z), f2bs(f.w) };
    *(short4v*)(dst + i) = s;
}

// ---------------------------------------------------------------------------
// Weight convert + transpose: W[k][n] fp32 -> wbT[z][n][k] bf16 (z = wq,wk,wv,wp)
// ---------------------------------------------------------------------------
__global__ __launch_bounds__(256) void convert_wT(
    const float* __restrict__ w0, const float* __restrict__ w1,
    const float* __restrict__ w2, const float* __restrict__ w3,
    short* __restrict__ wbT)
{
    const float* W = (blockIdx.z==0)?w0:(blockIdx.z==1)?w1:(blockIdx.z==2)?w2:w3;
    short* dst = wbT + (size_t)blockIdx.z * EMB * EMB;
    __shared__ float tile[64][65];
    const int k0 = blockIdx.x * 64;
    const int n0 = blockIdx.y * 64;
    const int tid = threadIdx.x;
    #pragma unroll
    for (int t = 0; t < 4; ++t) {
        int id = tid + t*256;
        int r = id >> 4, c4 = id & 15;
        float4 f = *(const float4*)(W + (size_t)(k0+r)*EMB + n0 + c4*4);
        tile[r][c4*4+0]=f.x; tile[r][c4*4+1]=f.y; tile[r][c4*4+2]=f.z; tile[r][c4*4+3]=f.w;
    }
    __syncthreads();
    #pragma unroll
    for (int t = 0; t < 4; ++t) {
        int id = tid + t*256;
        int n = id >> 4, k4 = id & 15;
        short4v s;
        #pragma unroll
        for (int j = 0; j < 4; ++j) s[j] = f2bs(tile[k4*4+j][n]);
        *(short4v*)(dst + (size_t)(n0+n)*EMB + k0 + k4*4) = s;
    }
}

// ---------------------------------------------------------------------------
// MFMA GEMM (m97 structure): C[4096, 3072] = xb @ wbT^T, split to q/k/v.
// ---------------------------------------------------------------------------
__global__ __launch_bounds__(256) void qkv_gemm_mfma(
    const short* __restrict__ xb, const short* __restrict__ wbT,
    short* __restrict__ qb, short* __restrict__ kb, short* __restrict__ vb)
{
    __shared__ short As[128*32];
    __shared__ short Bs[128*32];
    const int n0g = blockIdx.x * 128;
    const int m0  = blockIdx.y * 128;
    const int z   = n0g >> 10;
    short* C = (z==0)?qb:(z==1)?kb:vb;
    const int ncol0 = n0g & 1023;
    const int tid = threadIdx.x;
    const int wv = tid >> 6, lane = tid & 63;
    const int cl = lane & 15, q = lane >> 4;
    const int wm = wv >> 1, wn = wv & 1;
    const int lrow = lane >> 2;
    const int lcol = (lane & 3) * 8;
    float4v acc[4][4];
    #pragma unroll
    for (int mi=0;mi<4;++mi)
        #pragma unroll
        for (int ni=0;ni<4;++ni) acc[mi][ni]=(float4v){0.f,0.f,0.f,0.f};

    for (int k0 = 0; k0 < EMB; k0 += 32) {
        __syncthreads();
        #pragma unroll
        for (int t = 0; t < 2; ++t) {
            int chunk = wv*2 + t;
            gload16(xb  + (size_t)(m0  + chunk*16 + lrow)*EMB + k0 + lcol, &As[chunk*512]);
            gload16(wbT + (size_t)(n0g + chunk*16 + lrow)*EMB + k0 + lcol, &Bs[chunk*512]);
        }
        __syncthreads();
        short8 af[4], bfr[4];
        #pragma unroll
        for (int mi=0;mi<4;++mi) af[mi]  = *(const short8*)&As[(wm*64+mi*16+cl)*32 + q*8];
        #pragma unroll
        for (int ni=0;ni<4;++ni) bfr[ni] = *(const short8*)&Bs[(wn*64+ni*16+cl)*32 + q*8];
        #pragma unroll
        for (int mi=0;mi<4;++mi)
            #pragma unroll
            for (int ni=0;ni<4;++ni)
                acc[mi][ni] = __builtin_amdgcn_mfma_f32_16x16x32_bf16(af[mi], bfr[ni], acc[mi][ni], 0, 0, 0);
    }
    #pragma unroll
    for (int mi=0;mi<4;++mi)
        #pragma unroll
        for (int ni=0;ni<4;++ni)
            #pragma unroll
            for (int r=0;r<4;++r)
                C[(size_t)(m0+wm*64+mi*16+q*4+r)*EMB + ncol0 + wn*64+ni*16+cl] = f2bs(acc[mi][ni][r]);
}

// ---------------------------------------------------------------------------
// MFMA GEMM: out[4096,1024] fp32 = yb(bf16) @ wpT^T
// ---------------------------------------------------------------------------
__global__ __launch_bounds__(256) void proj_gemm_mfma(
    const short* __restrict__ yb, const short* __restrict__ wpT,
    float* __restrict__ out)
{
    __shared__ short As[128*32];
    __shared__ short Bs[128*32];
    const int n0 = blockIdx.x * 128;
    const int m0 = blockIdx.y * 128;
    const int tid = threadIdx.x;
    const int wv = tid >> 6, lane = tid & 63;
    const int cl = lane & 15, q = lane >> 4;
    const int wm = wv >> 1, wn = wv & 1;
    const int lrow = lane >> 2;
    const int lcol = (lane & 3) * 8;
    float4v acc[4][4];
    #pragma unroll
    for (int mi=0;mi<4;++mi)
        #pragma unroll
        for (int ni=0;ni<4;++ni) acc[mi][ni]=(float4v){0.f,0.f,0.f,0.f};

    for (int k0 = 0; k0 < EMB; k0 += 32) {
        __syncthreads();
        #pragma unroll
        for (int t = 0; t < 2; ++t) {
            int chunk = wv*2 + t;
            gload16(yb  + (size_t)(m0 + chunk*16 + lrow)*EMB + k0 + lcol, &As[chunk*512]);
            gload16(wpT + (size_t)(n0 + chunk*16 + lrow)*EMB + k0 + lcol, &Bs[chunk*512]);
        }
        __syncthreads();
        short8 af[4], bfr[4];
        #pragma unroll
        for (int mi=0;mi<4;++mi) af[mi]  = *(const short8*)&As[(wm*64+mi*16+cl)*32 + q*8];
        #pragma unroll
        for (int ni=0;ni<4;++ni) bfr[ni] = *(const short8*)&Bs[(wn*64+ni*16+cl)*32 + q*8];
        #pragma unroll
        for (int mi=0;mi<4;++mi)
            #pragma unroll
            for (int ni=0;ni<4;++ni)
                acc[mi][ni] = __builtin_amdgcn_mfma_f32_16x16x32_bf16(af[mi], bfr[ni], acc[mi][ni], 0, 0, 0);
    }
    #pragma unroll
    for (int mi=0;mi<4;++mi)
        #pragma unroll
        for (int ni=0;ni<4;++ni)
            #pragma unroll
            for (int r=0;r<4;++r)
                out[(size_t)(m0+wm*64+mi*16+q*4+r)*EMB + n0 + wn*64+ni*16+cl] = acc[mi][ni][r];
}

// ---------------------------------------------------------------------------
// RoPE + RMS-norm, in place on q/k bf16 buffers. 4 waves/block, wave = one (t,h)
// ---------------------------------------------------------------------------
__global__ __launch_bounds__(256) void rope_rms(
    bf16* __restrict__ qb, bf16* __restrict__ kb,
    const float* __restrict__ cosb, const float* __restrict__ sinb)
{
    const int wv = threadIdx.x >> 6;
    const int lane = threadIdx.x & 63;
    const int t = blockIdx.x * 4 + wv;
    const int h = blockIdx.y;
    bf16* base = (blockIdx.z ? kb : qb) + ((size_t)t*NH + h)*HD;
    const int d = lane;
    float x1 = b2f(base[d]), x2 = b2f(base[d+HALF]);
    float c = cosb[t*HALF + d];
    float s = sinb[t*HALF + d];
    float y1 = x1*c + x2*s;
    float y2 = x2*c - x1*s;
    float ss = y1*y1 + y2*y2;
    #pragma unroll
    for (int off = 32; off > 0; off >>= 1) ss += __shfl_down(ss, off);
    ss = __shfl(ss, 0);
    float r = rsqrtf(ss * (1.0f/HD) + 1e-6f);
    base[d]      = f2b(y1*r);
    base[d+HALF] = f2b(y2*r);
}

// ---------------------------------------------------------------------------
// Fused gate + ve-add + transpose: vt[h][d][t] = vb[t][h,d] + g(t,h)*ve[t][h,d]
// block: 64 t x 64 d (half-head) x head. Gate recomputed per block (trivial).
// ---------------------------------------------------------------------------
__global__ __launch_bounds__(256) void gate_vt(
    const float* __restrict__ x, const float* __restrict__ ve,
    const float* __restrict__ wg, const short* __restrict__ vb,
    short* __restrict__ vt)
{
    const int t0 = blockIdx.x * 64;
    const int d0 = blockIdx.y * 64;
    const int h  = blockIdx.z;
    const int tid = threadIdx.x;
    __shared__ short tile[64][68];
    __shared__ float g[64];
    if (tid < 64) {
        float s = 0.f;
        #pragma unroll
        for (int c = 0; c < 32; ++c)
            s += x[(size_t)(t0+tid)*EMB + c] * wg[c*NH + h];
        g[tid] = 2.f / (1.f + __expf(-s));
    }
    __syncthreads();
    #pragma unroll
    for (int k = 0; k < 4; ++k) {
        int id = tid + k*256;
        int r = id >> 4, c4 = id & 15;
        short4v vr = *(const short4v*)(vb + (size_t)(t0+r)*EMB + h*HD + d0 + c4*4);
        float4 vex = *(const float4*)(ve + (size_t)(t0+r)*EMB + h*HD + d0 + c4*4);
        float gr = g[r];
        short4v o;
        o[0] = f2bs(bs2f(vr[0]) + gr*vex.x);
        o[1] = f2bs(bs2f(vr[1]) + gr*vex.y);
        o[2] = f2bs(bs2f(vr[2]) + gr*vex.z);
        o[3] = f2bs(bs2f(vr[3]) + gr*vex.w);
        *(short4v*)&tile[r][c4*4] = o;
    }
    __syncthreads();
    #pragma unroll
    for (int k = 0; k < 4; ++k) {
        int id = tid + k*256;
        int dr = id >> 4, tg = id & 15;
        short4v w;
        #pragma unroll
        for (int j = 0; j < 4; ++j) w[j] = tile[tg*4+j][dr];
        *(short4v*)(vt + (size_t)(h*HD + d0 + dr)*T_SEQ + t0 + tg*4) = w;
    }
}

// ---------------------------------------------------------------------------
// Flash attention, MFMA 16x16x32 bf16. One block = 64 queries x 1 head.
// No-max softmax (|s| <= 11.33 since q,k RMS-normed) + pipelined K/V staging.
// ---------------------------------------------------------------------------
__global__ __launch_bounds__(256) void attn_flash(
    const bf16* __restrict__ qbh, const bf16* __restrict__ kbh,
    const bf16* __restrict__ vth, bf16* __restrict__ ybh,
    const int* __restrict__ wptr)
{
    const short* qb = (const short*)qbh;
    const short* kb = (const short*)kbh;
    const short* vt = (const short*)vth;
    short* yb = (short*)ybh;

    __shared__ short Ks[64*136];
    __shared__ short Vs[128*72];
    __shared__ short Ps[4*16*72];

    int W = *wptr; W = min(max(W, 1), 1024);
    const int i0 = blockIdx.x * 64;
    const int h  = blockIdx.y;
    const int tid  = threadIdx.x;
    const int wv   = tid >> 6;
    const int lane = tid & 63;
    const int cl   = lane & 15;
    const int q    = lane >> 4;
    const int m0   = wv * 16;
    const float scale = 0.08838834764831845f;

    short8 qa[4];
    {
        const short* qbase = qb + (size_t)(i0 + m0 + cl) * EMB + h*HD + q*8;
        #pragma unroll
        for (int ks = 0; ks < 4; ++ks)
            qa[ks] = *(const short8*)(qbase + ks*32);
    }

    float4v o[8];
    #pragma unroll
    for (int n = 0; n < 8; ++n) o[n] = (float4v){0.f,0.f,0.f,0.f};
    float lrow[4] = {0.f,0.f,0.f,0.f};

    const int lo_key  = i0 - W + 1;
    const int jt_start = lo_key > 0 ? (lo_key >> 6) : 0;
    const int jt_end   = i0 >> 6;

    // staging decode (constant per thread across tiles)
    const int kkey[4] = { (tid+0)>>4, (tid+256)>>4, (tid+512)>>4, (tid+768)>>4 };
    const int kc16 = tid & 15;
    const int vd[4] = { (tid+0)>>3, (tid+256)>>3, (tid+512)>>3, (tid+768)>>3 };
    const int vc8 = tid & 7;

    // prologue: prefetch first tile into registers
    short8 kreg[4], vreg[4];
    {
        const int j0 = jt_start << 6;
        #pragma unroll
        for (int kk = 0; kk < 4; ++kk) {
            kreg[kk] = *(const short8*)(kb + (size_t)(j0+kkey[kk])*EMB + h*HD + kc16*8);
            vreg[kk] = *(const short8*)(vt + (size_t)(h*HD + vd[kk])*T_SEQ + j0 + vc8*8);
        }
    }

    for (int jt = jt_start; jt <= jt_end; ++jt) {
        const int j0 = jt << 6;
        __syncthreads();   // previous tile's LDS reads complete
        #pragma unroll
        for (int kk = 0; kk < 4; ++kk) {
            *(short8*)&Ks[kkey[kk]*136 + kc16*8] = kreg[kk];
            *(short8*)&Vs[vd[kk]*72 + vc8*8]     = vreg[kk];
        }
        __syncthreads();
        // issue next tile's global loads; latency hides behind compute
        if (jt < jt_end) {
            const int j0n = j0 + 64;
            #pragma unroll
            for (int kk = 0; kk < 4; ++kk) {
                kreg[kk] = *(const short8*)(kb + (size_t)(j0n+kkey[kk])*EMB + h*HD + kc16*8);
                vreg[kk] = *(const short8*)(vt + (size_t)(h*HD + vd[kk])*T_SEQ + j0n + vc8*8);
            }
        }

        // S = Q K^T : 16x64 per wave
        float4v s[4];
        #pragma unroll
        for (int nt = 0; nt < 4; ++nt) {
            s[nt] = (float4v){0.f,0.f,0.f,0.f};
            #pragma unroll
            for (int ks = 0; ks < 4; ++ks) {
                short8 kf = *(const short8*)&Ks[(nt*16 + cl)*136 + ks*32 + q*8];
                s[nt] = __builtin_amdgcn_mfma_f32_16x16x32_bf16(qa[ks], kf, s[nt], 0, 0, 0);
            }
        }
        // scale + mask + exp (no max subtraction) + per-lane row-sum
        const bool needmask = (j0 + 63 > i0) || (j0 < i0 + 64 - W);
        #pragma unroll
        for (int nt = 0; nt < 4; ++nt) {
            #pragma unroll
            for (int r = 0; r < 4; ++r) {
                float sv = s[nt][r] * scale;
                if (needmask) {
                    int j    = j0 + nt*16 + cl;
                    int irow = i0 + m0 + q*4 + r;
                    if (j > irow || j <= irow - W) sv = -1e30f;
                }
                s[nt][r] = __expf(sv);
            }
        }
        #pragma unroll
        for (int r = 0; r < 4; ++r)
            lrow[r] += s[0][r] + s[1][r] + s[2][r] + s[3][r];
        // P -> LDS (C-layout -> A-layout transform)
        #pragma unroll
        for (int nt = 0; nt < 4; ++nt)
            #pragma unroll
            for (int r = 0; r < 4; ++r)
                Ps[wv*1152 + (q*4+r)*72 + nt*16 + cl] = f2bs(s[nt][r]);
        short8 pa[2];
        #pragma unroll
        for (int k2 = 0; k2 < 2; ++k2)
            pa[k2] = *(const short8*)&Ps[wv*1152 + cl*72 + k2*32 + q*8];
        // O += P V
        #pragma unroll
        for (int n = 0; n < 8; ++n) {
            #pragma unroll
            for (int k2 = 0; k2 < 2; ++k2) {
                short8 vf = *(const short8*)&Vs[(n*16 + cl)*72 + k2*32 + q*8];
                o[n] = __builtin_amdgcn_mfma_f32_16x16x32_bf16(pa[k2], vf, o[n], 0, 0, 0);
            }
        }
    }
    // epilogue: reduce row sums across the 16 lanes of each row, write O/l
    #pragma unroll
    for (int r = 0; r < 4; ++r) {
        float t = lrow[r];
        t += __shfl_xor(t, 1);
        t += __shfl_xor(t, 2);
        t += __shfl_xor(t, 4);
        t += __shfl_xor(t, 8);
        float inv = 1.f / t;
        int row = i0 + m0 + q*4 + r;
        #pragma unroll
        for (int n = 0; n < 8; ++n)
            yb[(size_t)row*EMB + h*HD + n*16 + cl] = f2bs(o[n][r] * inv);
    }
}

// ---------------------------------------------------------------------------
extern "C" void kernel_launch(void* const* d_in, const int* in_sizes, int n_in,
                              void* d_out, int out_size, void* d_ws, size_t ws_size,
                              hipStream_t stream)
{
    const float* x    = (const float*)d_in[0];
    const float* ve   = (const float*)d_in[1];
    const float* cosb = (const float*)d_in[2];
    const float* sinb = (const float*)d_in[3];
    const float* wq   = (const float*)d_in[4];
    const float* wk   = (const float*)d_in[5];
    const float* wv   = (const float*)d_in[6];
    const float* wg   = (const float*)d_in[7];
    const float* wp   = (const float*)d_in[8];
    const int*   wsz  = (const int*)d_in[9];
    float* out = (float*)d_out;

    const size_t SEG = (size_t)T_SEQ * EMB;        // 4M elements = 8 MB bf16
    short* xb  = (short*)d_ws;                     // later reused as vt
    short* wbT = xb + SEG;                         // wq|wk|wv|wp transposed, 4x1M
    short* qb  = wbT + SEG;
    short* kb  = qb + SEG;
    short* vb  = kb + SEG;                         // 40 MB total
    short* vt  = xb;                               // alias: xb dead after qkv gemm
    short* yb  = vb;                               // alias: vb dead after gate_vt

    convert_x<<<T_SEQ*EMB/1024, 256, 0, stream>>>(x, xb);
    convert_wT<<<dim3(16, 16, 4), 256, 0, stream>>>(wq, wk, wv, wp, wbT);
    qkv_gemm_mfma<<<dim3(24, 32), 256, 0, stream>>>(xb, wbT, qb, kb, vb);
    rope_rms<<<dim3(T_SEQ/4, NH, 2), 256, 0, stream>>>((bf16*)qb, (bf16*)kb, cosb, sinb);
    gate_vt<<<dim3(T_SEQ/64, HD/64, NH), 256, 0, stream>>>(x, ve, wg, vb, vt);
    attn_flash<<<dim3(T_SEQ/64, NH), 256, 0, stream>>>((bf16*)qb, (bf16*)kb, (bf16*)vt, (bf16*)yb, wsz);
    proj_gemm_mfma<<<dim3(8, 32), 256, 0, stream>>>(yb, wbT + (size_t)3*EMB*EMB, out);
}